// Round 5
// baseline (449.707 us; speedup 1.0000x reference)
//
#include <hip/hip_runtime.h>
#include <math.h>

#define F_IN 256
#define HID  64
#define BSH  8              // bucket = dst >> 8 (256 nodes per bucket)
#define BSPAN 256
#define CHUNK 16384         // edges per sort block (64 per thread)
#define NBK_MAX 512

typedef __bf16 bf16x8 __attribute__((ext_vector_type(8)));
typedef float  floatx4 __attribute__((ext_vector_type(4)));

// ---------------------------------------------------------------------------
// Pass 1: per-chunk histogram over coarse dst buckets
// ---------------------------------------------------------------------------
__global__ __launch_bounds__(256) void k_hist(const int* __restrict__ dst,
                                              int* __restrict__ cntT,
                                              int E, int NCH, int NBK) {
    __shared__ int hist[NBK_MAX];
    int t = threadIdx.x, c = blockIdx.x;
    hist[t] = 0; hist[t + 256] = 0;
    __syncthreads();
    int base = c * CHUNK;
#pragma unroll 4
    for (int j = 0; j < CHUNK / 256; j++) {
        int e = base + j * 256 + t;
        if (e < E) atomicAdd(&hist[dst[e] >> BSH], 1);
    }
    __syncthreads();
    for (int b = t; b < NBK; b += 256) cntT[b * NCH + c] = hist[b];
}

// ---------------------------------------------------------------------------
// Exclusive scan of cntT (S elements) -> off, plus sentinel off[S] = total
// ---------------------------------------------------------------------------
__global__ __launch_bounds__(256) void k_scanA(const int* __restrict__ cntT,
                                               int* __restrict__ off,
                                               int* __restrict__ partials, int S) {
    __shared__ int sh[256];
    int tid = threadIdx.x;
    int base = blockIdx.x * 1024 + tid * 4;
    int v[4];
    int s = 0;
#pragma unroll
    for (int j = 0; j < 4; j++) {
        int idx = base + j;
        v[j] = (idx < S) ? cntT[idx] : 0;
        s += v[j];
    }
    sh[tid] = s;
    __syncthreads();
    int mysum = s;
    for (int o = 1; o < 256; o <<= 1) {
        int tv = (tid >= o) ? sh[tid - o] : 0;
        __syncthreads();
        sh[tid] += tv;
        __syncthreads();
    }
    int pref = sh[tid] - mysum;
#pragma unroll
    for (int j = 0; j < 4; j++) {
        int idx = base + j;
        if (idx < S) off[idx] = pref;
        pref += v[j];
    }
    if (tid == 255) partials[blockIdx.x] = sh[255];
}

__global__ void k_scanB(int* __restrict__ partials, int* __restrict__ off,
                        int nblk, int S) {
    if (blockIdx.x == 0 && threadIdx.x == 0) {
        int run = 0;
        for (int b = 0; b < nblk; b++) { int t = partials[b]; partials[b] = run; run += t; }
        off[S] = run;   // == E
    }
}

__global__ void k_scanC(int* __restrict__ off, const int* __restrict__ partials, int S) {
    int i = blockIdx.x * blockDim.x + threadIdx.x;
    if (i < S) off[i] += partials[i >> 10];
}

// ---------------------------------------------------------------------------
// Pass 2: scatter edges into bucket-grouped ebuf. Entry = (src<<8)|(dst&255)
// ---------------------------------------------------------------------------
__global__ __launch_bounds__(256) void k_sortwrite(const int* __restrict__ src,
                                                   const int* __restrict__ dst,
                                                   const int* __restrict__ off,
                                                   int* __restrict__ ebuf,
                                                   int E, int NCH, int NBK) {
    __shared__ int cur[NBK_MAX];
    int t = threadIdx.x, c = blockIdx.x;
    for (int b = t; b < NBK; b += 256) cur[b] = off[b * NCH + c];
    __syncthreads();
    int base = c * CHUNK;
#pragma unroll 4
    for (int j = 0; j < CHUNK / 256; j++) {
        int e = base + j * 256 + t;
        if (e < E) {
            int s = src[e];
            int d = dst[e];
            int pos = atomicAdd(&cur[d >> BSH], 1);
            ebuf[pos] = (s << BSH) | (d & (BSPAN - 1));
        }
    }
}

// ---------------------------------------------------------------------------
// Pass 3: per-bucket node-level CSR: rp, dinv, node-sorted esrc
// ---------------------------------------------------------------------------
__global__ __launch_bounds__(256) void k_bucket_csr(const int* __restrict__ off,
                                                    const int* __restrict__ ebuf,
                                                    int* __restrict__ rp,
                                                    float* __restrict__ dinv,
                                                    int* __restrict__ esrc,
                                                    int N, int NCH, int NBK) {
    __shared__ int cnt[BSPAN];
    __shared__ int sh[BSPAN];
    int b = blockIdx.x, t = threadIdx.x;
    int base = off[b * NCH];
    int end  = off[(b + 1) * NCH];

    cnt[t] = 0;
    __syncthreads();
    for (int i = base + t; i < end; i += 256) atomicAdd(&cnt[ebuf[i] & (BSPAN - 1)], 1);
    __syncthreads();

    int c = cnt[t];
    sh[t] = c;
    __syncthreads();
    for (int o = 1; o < 256; o <<= 1) {
        int tv = (t >= o) ? sh[t - o] : 0;
        __syncthreads();
        sh[t] += tv;
        __syncthreads();
    }
    int excl = sh[t] - c;

    int node = (b << BSH) + t;
    if (node < N) {
        rp[node] = base + excl;
        dinv[node] = rsqrtf((float)(1 + c));
    }
    if (b == NBK - 1 && t == 0) rp[N] = end;
    __syncthreads();

    cnt[t] = base + excl;
    __syncthreads();
    for (int i = base + t; i < end; i += 256) {
        int v = ebuf[i];
        int p = atomicAdd(&cnt[v & (BSPAN - 1)], 1);
        esrc[p] = v >> BSH;
    }
}

// ---------------------------------------------------------------------------
// One-time weight prep: W[K x 64] -> transposed split-bf16 Bt_hi/Bt_lo [64 x K]
// ---------------------------------------------------------------------------
__global__ __launch_bounds__(256) void k_prepw(const float* __restrict__ W1,
                                               __bf16* __restrict__ w1h, __bf16* __restrict__ w1l,
                                               const float* __restrict__ W2,
                                               __bf16* __restrict__ w2h, __bf16* __restrict__ w2l) {
    int t = threadIdx.x + blockIdx.x * blockDim.x;
    // W1: 64 cols x 256 k
    for (int idx = t; idx < 64 * 256; idx += 256 * 8) {
        int c = idx >> 8, k = idx & 255;
        float w = W1[k * 64 + c];
        __bf16 h = (__bf16)w;
        w1h[idx] = h;
        w1l[idx] = (__bf16)(w - (float)h);
    }
    // W2: 64 cols x 64 k
    for (int idx = t; idx < 64 * 64; idx += 256 * 8) {
        int c = idx >> 6, k = idx & 63;
        float w = W2[k * 64 + c];
        __bf16 h = (__bf16)w;
        w2h[idx] = h;
        w2l[idx] = (__bf16)(w - (float)h);
    }
}

// ---------------------------------------------------------------------------
// Split-bf16 MFMA GEMM: C[nrows x 64] = (A[nrows x K] @ B[K x 64]) * dinv[row]
// A fp32 (split in-register), B pre-split transposed bf16 [64 x K].
// One wave per 16 output rows; no LDS, no barriers.
//   D = Ah*Bh + Ah*Bl + Al*Bh   (Al*Bl ~2^-18 dropped)
// mfma_f32_16x16x32_bf16 layouts (HW-verified): A[m=lane&15][k=q*8+j],
// Bt[n=lane&15][k=q*8+j], C/D: col=lane&15, row=q*4+reg.
// ---------------------------------------------------------------------------
template <int K>
__global__ __launch_bounds__(256) void k_gemm_mfma(const float* __restrict__ A,
                                                   const __bf16* __restrict__ BtH,
                                                   const __bf16* __restrict__ BtL,
                                                   const float* __restrict__ dinv,
                                                   float* __restrict__ C, int nrows) {
    int wave = threadIdx.x >> 6;
    int lane = threadIdx.x & 63;
    int m = lane & 15;
    int q = lane >> 4;
    int row0 = blockIdx.x * 64 + wave * 16;
    int arow = row0 + m;
    bool rvalid = arow < nrows;
    const float* ap = A + (size_t)arow * K + q * 8;

    floatx4 acc[4] = {{0.f, 0.f, 0.f, 0.f}, {0.f, 0.f, 0.f, 0.f},
                      {0.f, 0.f, 0.f, 0.f}, {0.f, 0.f, 0.f, 0.f}};

    for (int k0 = 0; k0 < K; k0 += 32) {
        float4 f0 = make_float4(0.f, 0.f, 0.f, 0.f);
        float4 f1 = make_float4(0.f, 0.f, 0.f, 0.f);
        if (rvalid) {
            f0 = *(const float4*)(ap + k0);
            f1 = *(const float4*)(ap + k0 + 4);
        }
        float af[8] = {f0.x, f0.y, f0.z, f0.w, f1.x, f1.y, f1.z, f1.w};
        bf16x8 ah, al;
#pragma unroll
        for (int j = 0; j < 8; j++) {
            __bf16 h = (__bf16)af[j];
            ah[j] = h;
            al[j] = (__bf16)(af[j] - (float)h);
        }
#pragma unroll
        for (int c = 0; c < 4; c++) {
            const __bf16* bp = BtH + (size_t)(c * 16 + m) * K + k0 + q * 8;
            const __bf16* bq = BtL + (size_t)(c * 16 + m) * K + k0 + q * 8;
            bf16x8 bh = *(const bf16x8*)bp;
            bf16x8 bl = *(const bf16x8*)bq;
            acc[c] = __builtin_amdgcn_mfma_f32_16x16x32_bf16(ah, bh, acc[c], 0, 0, 0);
            acc[c] = __builtin_amdgcn_mfma_f32_16x16x32_bf16(al, bh, acc[c], 0, 0, 0);
            acc[c] = __builtin_amdgcn_mfma_f32_16x16x32_bf16(ah, bl, acc[c], 0, 0, 0);
        }
    }

#pragma unroll
    for (int i = 0; i < 4; i++) {
        int r = row0 + q * 4 + i;
        if (r < nrows) {
            float di = dinv[r];
#pragma unroll
            for (int c = 0; c < 4; c++)
                C[(size_t)r * 64 + c * 16 + m] = acc[c][i] * di;
        }
    }
}

// ---------------------------------------------------------------------------
// Aggregation over CSR, 64 features, one wave per node, 8-deep MLP.
// ---------------------------------------------------------------------------
template <int MODE>
__global__ __launch_bounds__(256) void k_agg64(const float* __restrict__ hs,
                                               const float* __restrict__ dinv,
                                               const int* __restrict__ rp,
                                               const int* __restrict__ esrc,
                                               const float* __restrict__ bias,
                                               const float* __restrict__ W3,
                                               float* __restrict__ out, int n) {
    int lane = threadIdx.x & 63;
    int nid = blockIdx.x * 4 + (threadIdx.x >> 6);
    if (nid >= n) return;
    nid = __builtin_amdgcn_readfirstlane(nid);

    float dii = dinv[nid];
    int e0 = rp[nid];
    int e1 = rp[nid + 1];

    float a0 = hs[(size_t)nid * 64 + lane];
    float a1 = 0.f, a2 = 0.f, a3 = 0.f, a4 = 0.f, a5 = 0.f, a6 = 0.f, a7 = 0.f;

    for (int e = e0; e < e1; e += 8) {
        int last = e1 - 1;
        int i0 = esrc[e];
        int i1 = esrc[min(e + 1, last)];
        int i2 = esrc[min(e + 2, last)];
        int i3 = esrc[min(e + 3, last)];
        int i4 = esrc[min(e + 4, last)];
        int i5 = esrc[min(e + 5, last)];
        int i6 = esrc[min(e + 6, last)];
        int i7 = esrc[min(e + 7, last)];
        float v0 = hs[(size_t)i0 * 64 + lane];
        float v1 = hs[(size_t)i1 * 64 + lane];
        float v2 = hs[(size_t)i2 * 64 + lane];
        float v3 = hs[(size_t)i3 * 64 + lane];
        float v4 = hs[(size_t)i4 * 64 + lane];
        float v5 = hs[(size_t)i5 * 64 + lane];
        float v6 = hs[(size_t)i6 * 64 + lane];
        float v7 = hs[(size_t)i7 * 64 + lane];
        a0 += v0;
        a1 += (e + 1 <= last) ? v1 : 0.f;
        a2 += (e + 2 <= last) ? v2 : 0.f;
        a3 += (e + 3 <= last) ? v3 : 0.f;
        a4 += (e + 4 <= last) ? v4 : 0.f;
        a5 += (e + 5 <= last) ? v5 : 0.f;
        a6 += (e + 6 <= last) ? v6 : 0.f;
        a7 += (e + 7 <= last) ? v7 : 0.f;
    }

    float acc = ((a0 + a1) + (a2 + a3)) + ((a4 + a5) + (a6 + a7));
    acc = acc * dii + bias[lane];
    acc = fmaxf(acc, 0.f);

    if (MODE == 0) {
        out[(size_t)nid * 64 + lane] = acc;
    } else {
        float2 w3 = ((const float2*)W3)[lane];
        float p0 = acc * w3.x;
        float p1 = acc * w3.y;
#pragma unroll
        for (int o = 32; o > 0; o >>= 1) {
            p0 += __shfl_xor(p0, o, 64);
            p1 += __shfl_xor(p1, o, 64);
        }
        if (lane == 0) ((float2*)out)[nid] = make_float2(p0 * dii, p1 * dii);
    }
}

// ---------------------------------------------------------------------------
// Final layer: 2-wide aggregation + bias + log_softmax (thread per node)
// ---------------------------------------------------------------------------
__global__ __launch_bounds__(256) void k_final(const float2* __restrict__ h3s,
                                               const float* __restrict__ dinv,
                                               const int* __restrict__ rp,
                                               const int* __restrict__ esrc,
                                               const float* __restrict__ b3,
                                               float* __restrict__ out, int n) {
    int i = blockIdx.x * blockDim.x + threadIdx.x;
    if (i >= n) return;
    float dii = dinv[i];
    float2 h = h3s[i];
    float ax = h.x, ay = h.y;
    float bx = 0.f, by = 0.f, cx = 0.f, cy = 0.f, dx = 0.f, dy = 0.f;
    int e0 = rp[i], e1 = rp[i + 1];
    for (int e = e0; e < e1; e += 4) {
        int last = e1 - 1;
        int s0 = esrc[e];
        int s1 = esrc[min(e + 1, last)];
        int s2 = esrc[min(e + 2, last)];
        int s3 = esrc[min(e + 3, last)];
        float2 v0 = h3s[s0];
        float2 v1 = h3s[s1];
        float2 v2 = h3s[s2];
        float2 v3 = h3s[s3];
        ax += v0.x; ay += v0.y;
        bx += (e + 1 <= last) ? v1.x : 0.f; by += (e + 1 <= last) ? v1.y : 0.f;
        cx += (e + 2 <= last) ? v2.x : 0.f; cy += (e + 2 <= last) ? v2.y : 0.f;
        dx += (e + 3 <= last) ? v3.x : 0.f; dy += (e + 3 <= last) ? v3.y : 0.f;
    }
    float l0 = ((ax + bx) + (cx + dx)) * dii + b3[0];
    float l1 = ((ay + by) + (cy + dy)) * dii + b3[1];
    float m = fmaxf(l0, l1);
    float lse = m + logf(expf(l0 - m) + expf(l1 - m));
    ((float2*)out)[i] = make_float2(l0 - lse, l1 - lse);
}

// ---------------------------------------------------------------------------
// Launch
// ---------------------------------------------------------------------------
extern "C" void kernel_launch(void* const* d_in, const int* in_sizes, int n_in,
                              void* d_out, int out_size, void* d_ws, size_t ws_size,
                              hipStream_t stream) {
    const float* x   = (const float*)d_in[0];
    const int*   ei  = (const int*)d_in[1];
    const float* W1  = (const float*)d_in[2];
    const float* b1  = (const float*)d_in[3];
    const float* W2  = (const float*)d_in[4];
    const float* b2  = (const float*)d_in[5];
    const float* W3  = (const float*)d_in[6];
    const float* b3  = (const float*)d_in[7];
    float* out = (float*)d_out;

    const int N = in_sizes[0] / F_IN;   // 100000
    const int E = in_sizes[1] / 2;      // 1600000
    const int* src = ei;
    const int* dst = ei + E;

    const int NBK = (N + BSPAN - 1) / BSPAN;      // 391
    const int NCH = (E + CHUNK - 1) / CHUNK;      // 98
    const int S   = NBK * NCH;

    // workspace bump allocator (256B aligned)
    char* p = (char*)d_ws;
    auto alloc = [&](size_t bytes) -> void* {
        void* r = (void*)p;
        p += (bytes + 255) & ~(size_t)255;
        return r;
    };
    int*    cntT     = (int*)alloc((size_t)S * 4);
    int*    off      = (int*)alloc((size_t)(S + 1) * 4);
    int*    partials = (int*)alloc(4096);
    int*    ebuf     = (int*)alloc((size_t)E * 4);
    int*    esrc     = (int*)alloc((size_t)E * 4);
    int*    rp       = (int*)alloc((size_t)(N + 1) * 4);
    float*  dinv     = (float*)alloc((size_t)N * 4);
    float*  bufA     = (float*)alloc((size_t)N * HID * 4);
    float*  bufB     = (float*)alloc((size_t)N * HID * 4);
    float*  h3       = (float*)alloc((size_t)N * 2 * 4);
    __bf16* w1h      = (__bf16*)alloc(64 * 256 * 2);
    __bf16* w1l      = (__bf16*)alloc(64 * 256 * 2);
    __bf16* w2h      = (__bf16*)alloc(64 * 64 * 2);
    __bf16* w2l      = (__bf16*)alloc(64 * 64 * 2);

    const int T = 256;
    int scanBlocks = (S + 1023) / 1024;

    // weight prep (independent of CSR chain)
    k_prepw<<<8, T, 0, stream>>>(W1, w1h, w1l, W2, w2h, w2l);

    // CSR build via locality-aware counting sort
    k_hist<<<NCH, T, 0, stream>>>(dst, cntT, E, NCH, NBK);
    k_scanA<<<scanBlocks, T, 0, stream>>>(cntT, off, partials, S);
    k_scanB<<<1, 64, 0, stream>>>(partials, off, scanBlocks, S);
    k_scanC<<<(S + T - 1) / T, T, 0, stream>>>(off, partials, S);
    k_sortwrite<<<NCH, T, 0, stream>>>(src, dst, off, ebuf, E, NCH, NBK);
    k_bucket_csr<<<NBK, T, 0, stream>>>(off, ebuf, rp, dinv, esrc, N, NCH, NBK);

    // layer 1
    int gemmBlocks = (N + 63) / 64;
    k_gemm_mfma<F_IN><<<gemmBlocks, T, 0, stream>>>(x, w1h, w1l, dinv, bufA, N);
    k_agg64<0><<<(N + 3) / 4, T, 0, stream>>>(bufA, dinv, rp, esrc, b1, nullptr, bufB, N);

    // layer 2 (+ fused GEMM3)
    k_gemm_mfma<HID><<<gemmBlocks, T, 0, stream>>>(bufB, w2h, w2l, dinv, bufA, N);
    k_agg64<1><<<(N + 3) / 4, T, 0, stream>>>(bufA, dinv, rp, esrc, b2, W3, h3, N);

    // layer 3 + log_softmax
    k_final<<<(N + T - 1) / T, T, 0, stream>>>((const float2*)h3, dinv, rp, esrc, b3, out, N);
}